// Round 7
// baseline (111.298 us; speedup 1.0000x reference)
//
#include <hip/hip_runtime.h>
#include <math.h>

// Problem constants (fixed by the reference):
#define B_ 4
#define C_ 192
#define L_ 4096
#define CO_ 64
#define LOG2E 1.44269504088896340736f

using half8 = __attribute__((ext_vector_type(8))) _Float16;
using half4v = __attribute__((ext_vector_type(4))) _Float16;
using half2v = __attribute__((ext_vector_type(2))) _Float16;
using f32x16 = __attribute__((ext_vector_type(16))) float;

#if __has_builtin(__builtin_amdgcn_exp2f)
#define EXP2(x) __builtin_amdgcn_exp2f(x)
#else
#define EXP2(x) exp2f(x)
#endif

__device__ inline half2v pkrtz(float a, float b) {
  return __builtin_bit_cast(half2v, __builtin_amdgcn_cvt_pkrtz(a, b));
}

// ---------------------------------------------------------------------------
// ws layout (halfs unless noted; fully rewritten every call):
//   fPack : [b][T][ks][lane]x8   4*128*4*64*8 = 2 MB  (A-frags of f, xLOG2E)
//   gPack : [b][T][ks][lane]x8                = 2 MB  (B-frags of g, T=32-m chunk)
//   hPack : [b][T][j][lane]x8                 = 2 MB  (A/B-frags of h)
//   v1N   : [b][o][l] f32                     = 4 MB
// All attn loads are lane-contiguous 1-KB fragment loads (dense lines).
// ---------------------------------------------------------------------------

// ---------------------------------------------------------------------------
// Kernel 1: projections via MFMA.  Grid (L/32=T, B), 256 thr (4 waves).
// W frags built in-kernel from global fp32 (strided float4, L2-hit).
// x staged f32 [c][l] via global_load_lds.
// Wave 0 (f): swapped operands D[l][o] -> LDS transpose -> fPack frags.
// Wave 1 (g): swapped operands D[l][o] -> LDS transpose -> gPack frags.
// Wave 2 (h): normal D[o][l] -> LDS transpose -> hPack frags.
// Wave 3 (v1): normal -> direct [o][l] f32 stores.
// ---------------------------------------------------------------------------
__global__ __launch_bounds__(256) void proj_mfma(
    const float* __restrict__ x, const float* __restrict__ Wq,
    const float* __restrict__ Wk, const float* __restrict__ Wv,
    const float* __restrict__ Wv1, _Float16* __restrict__ fPack,
    _Float16* __restrict__ gPack, _Float16* __restrict__ hPack,
    float* __restrict__ v1N) {
  __shared__ __align__(16) float xs[C_ * 32];       // [c][l] rows of 128 B
  __shared__ __align__(16) _Float16 fl[32 * 72];    // wave-0 transpose buffer
  __shared__ __align__(16) _Float16 gl[32 * 72];    // wave-1 transpose buffer
  __shared__ __align__(16) _Float16 hl[64 * 40];    // wave-2 transpose buffer
  const int b = blockIdx.y, T = blockIdx.x, l0 = T * 32;
  const int t = threadIdx.x;
  const int lane = t & 63, w = t >> 6;
  const int m = lane & 31, hi = lane >> 5;

  {  // stage x: wave w loads c-range [48w, 48w+48)
    const float* xb = x + (size_t)b * C_ * L_ + l0;
    const int c0 = w * 48;
#pragma unroll
    for (int i = 0; i < 6; ++i) {
      const int cc = c0 + i * 8;
      const float* gp = xb + (size_t)(cc + (lane >> 3)) * L_ + (lane & 7) * 4;
      __builtin_amdgcn_global_load_lds(
          (const __attribute__((address_space(1))) void*)gp,
          (__attribute__((address_space(3))) void*)&xs[cc * 32], 16, 0, 0);
    }
  }

  // W frags from global fp32 (independent of xs; overlaps the DMA)
  const float* Wsrc = (w == 0) ? Wq : (w == 1) ? Wk : (w == 2) ? Wv : Wv1;
  const float ws = (w == 0) ? LOG2E : 1.0f;
  half8 wf[2][12];
#pragma unroll
  for (int og = 0; og < 2; ++og)
#pragma unroll
    for (int ks = 0; ks < 12; ++ks) {
      const float* p = Wsrc + (og * 32 + m) * C_ + ks * 16 + hi * 8;
      const float4 a = *(const float4*)p;
      const float4 c = *(const float4*)(p + 4);
      half2v h;
      h = pkrtz(a.x * ws, a.y * ws); wf[og][ks][0] = h[0]; wf[og][ks][1] = h[1];
      h = pkrtz(a.z * ws, a.w * ws); wf[og][ks][2] = h[0]; wf[og][ks][3] = h[1];
      h = pkrtz(c.x * ws, c.y * ws); wf[og][ks][4] = h[0]; wf[og][ks][5] = h[1];
      h = pkrtz(c.z * ws, c.w * ws); wf[og][ks][6] = h[0]; wf[og][ks][7] = h[1];
    }
  __syncthreads();

  if (w < 2) {
    // D[l][o] = x^T W^T : A = x^T rows l, B = W^T cols o.
    f32x16 acc0 = {}, acc1 = {};
#pragma unroll
    for (int ks = 0; ks < 12; ++ks) {
      const float* xr = &xs[(ks * 16 + hi * 8) * 32 + m];
      half8 aF;
#pragma unroll
      for (int e = 0; e < 8; e += 2) {
        const half2v hp = pkrtz(xr[e * 32], xr[(e + 1) * 32]);
        aF[e] = hp[0]; aF[e + 1] = hp[1];
      }
      acc0 = __builtin_amdgcn_mfma_f32_32x32x16_f16(aF, wf[0][ks], acc0, 0, 0, 0);
      acc1 = __builtin_amdgcn_mfma_f32_32x32x16_f16(aF, wf[1][ks], acc1, 0, 0, 0);
    }
    // transpose via per-wave LDS, then fragment-packed lane-contiguous stores
    _Float16* buf = (w == 0) ? fl : gl;
#pragma unroll
    for (int r = 0; r < 16; ++r) {
      const int l = 4 * hi + 8 * (r >> 2) + (r & 3);
      buf[l * 72 + m] = (_Float16)acc0[r];
      buf[l * 72 + 32 + m] = (_Float16)acc1[r];
    }
    _Float16* dst = ((w == 0) ? fPack : gPack) +
                    (size_t)b * L_ * CO_ + (size_t)T * 4 * 64 * 8;
#pragma unroll
    for (int ks = 0; ks < 4; ++ks) {
      const half8 v =
          *(const half8*)&buf[(lane & 31) * 72 + ks * 16 + (lane >> 5) * 8];
      *(half8*)(dst + ((size_t)ks * 64 + lane) * 8) = v;
    }
  } else {
    // D[o][l] = W x : A = W rows o, B = x cols l.
    const int lg = l0 + m;
    for (int oh = 0; oh < 2; ++oh) {
      f32x16 acc = {};
#pragma unroll
      for (int ks = 0; ks < 12; ++ks) {
        const float* xr = &xs[(16 * ks + 8 * hi) * 32 + m];
        half8 bF;
#pragma unroll
        for (int e = 0; e < 8; e += 2) {
          const half2v hp = pkrtz(xr[e * 32], xr[(e + 1) * 32]);
          bF[e] = hp[0]; bF[e + 1] = hp[1];
        }
        acc = __builtin_amdgcn_mfma_f32_32x32x16_f16(wf[oh][ks], bF, acc, 0, 0, 0);
      }
      if (w == 2) {
#pragma unroll
        for (int r = 0; r < 16; ++r) {
          const int o = 32 * oh + 4 * hi + 8 * (r >> 2) + (r & 3);
          hl[o * 40 + m] = (_Float16)acc[r];
        }
      } else {
#pragma unroll
        for (int r = 0; r < 16; ++r) {
          const int o = 32 * oh + 4 * hi + 8 * (r >> 2) + (r & 3);
          v1N[((size_t)b * CO_ + o) * L_ + lg] = acc[r];
        }
      }
    }
    if (w == 2) {  // fragment-packed stores
      _Float16* dst = hPack + (size_t)b * L_ * CO_ + (size_t)T * 4 * 64 * 8;
#pragma unroll
      for (int j = 0; j < 4; ++j) {  // j = oh*2 + ks
        const int oh2 = j >> 1, ks2 = j & 1;
        const half8 v = *(const half8*)&hl[(32 * oh2 + (lane & 31)) * 40 +
                                           ks2 * 16 + (lane >> 5) * 8];
        *(half8*)(dst + ((size_t)j * 64 + lane) * 8) = v;
      }
    }
  }
}

// ---------------------------------------------------------------------------
// Kernel 2: flash attention, fragment-packed loads, fused dual softmax.
// 256 blocks (1/CU; XCD pair -> batch), 512 thr = 8 waves.
// Wave s: l-partition [512s, 512s+512), 16 steps of 32 l x 64 m.
// Per step: 8 S-MFMA, then ONE fused softmax body for both m-halves
// (both max trees, both exp blocks, all 8 P-writes -> single LDS wait leg
// -> 4 P-reads -> 8 O-MFMA).  Register-double-buffered f/h frags.
// ---------------------------------------------------------------------------
__global__ __launch_bounds__(512, 2) void attn_mfma(
    const _Float16* __restrict__ fPack, const _Float16* __restrict__ gPack,
    const _Float16* __restrict__ hPack, const float* __restrict__ v1N,
    const float* __restrict__ gamma_p, float* __restrict__ out) {
  __shared__ __align__(16) _Float16 Pl[8][64 * 40];  // per-wave P, 2 m-halves
  __shared__ float obuf4[4][CO_][65];
  __shared__ float redM[8][64];
  __shared__ float redZ[8][64];

  const int id = blockIdx.x;                   // 256 blocks
  const int b = (id >> 1) & 3;                 // XCD pair -> batch
  const int mt = ((id & 1) << 5) | (id >> 3);  // 0..63
  const int m0 = mt * 64;
  const int t = threadIdx.x;
  const int lane = t & 63, s = t >> 6;
  const int m = lane & 31, hi = lane >> 5;

  const _Float16* fT = fPack + (size_t)b * L_ * CO_;
  const _Float16* hT = hPack + (size_t)b * L_ * CO_;
  _Float16* Pw = &Pl[s][0];

  // loop-invariant g B-frags for both m-halves (lane-contiguous frag loads)
  half8 gf0[4], gf1[4];
  {
    const _Float16* gp = gPack + (size_t)b * L_ * CO_ +
                         (size_t)(2 * mt) * 4 * 64 * 8 + lane * 8;
#pragma unroll
    for (int ks = 0; ks < 4; ++ks) {
      gf0[ks] = *(const half8*)(gp + (size_t)ks * 64 * 8);
      gf1[ks] = *(const half8*)(gp + (size_t)(4 + ks) * 64 * 8);
    }
  }

  f32x16 o0 = {}, o1 = {}, o2 = {}, o3 = {};
  float mx0 = -1e30f, Z0 = 0.f, mx1 = -1e30f, Z1 = 0.f;

  const int T0 = s * 16;
  half8 fc[2][4], hc[2][4];
  {  // initial frags, step 0
    const _Float16* fp = fT + ((size_t)T0 * 4 * 64 + lane) * 8;
    const _Float16* hp = hT + ((size_t)T0 * 4 * 64 + lane) * 8;
#pragma unroll
    for (int ks = 0; ks < 4; ++ks) {
      fc[0][ks] = *(const half8*)(fp + (size_t)ks * 64 * 8);
      hc[0][ks] = *(const half8*)(hp + (size_t)ks * 64 * 8);
    }
  }

#pragma unroll 2
  for (int stp = 0; stp < 16; ++stp) {
    const int cur = stp & 1, nxt = cur ^ 1;
    {  // prefetch step+1 (tail reads run into the next ws buffer: harmless)
      const int Tn = T0 + stp + 1;
      const _Float16* fp = fT + ((size_t)Tn * 4 * 64 + lane) * 8;
      const _Float16* hp = hT + ((size_t)Tn * 4 * 64 + lane) * 8;
#pragma unroll
      for (int ks = 0; ks < 4; ++ks) {
        fc[nxt][ks] = *(const half8*)(fp + (size_t)ks * 64 * 8);
        hc[nxt][ks] = *(const half8*)(hp + (size_t)ks * 64 * 8);
      }
    }
    // S for both m-halves (scores in log2 units via Wq pre-scale)
    f32x16 S0 = {}, S1 = {};
#pragma unroll
    for (int ks = 0; ks < 4; ++ks) {
      S0 = __builtin_amdgcn_mfma_f32_32x32x16_f16(fc[cur][ks], gf0[ks], S0, 0, 0, 0);
      S1 = __builtin_amdgcn_mfma_f32_32x32x16_f16(fc[cur][ks], gf1[ks], S1, 0, 0, 0);
    }
    // ---- fused dual online softmax ----
    float t0 = S0[0], t1 = S1[0];
#pragma unroll
    for (int r = 1; r < 16; ++r) {
      t0 = fmaxf(t0, S0[r]);
      t1 = fmaxf(t1, S1[r]);
    }
    t0 = fmaxf(t0, __shfl_xor(t0, 32, 64));
    t1 = fmaxf(t1, __shfl_xor(t1, 32, 64));
    if (__any(t0 > mx0 || t1 > mx1)) {
      const float mn0 = fmaxf(mx0, t0), mn1 = fmaxf(mx1, t1);
      const float c0 = EXP2(mx0 - mn0), c1 = EXP2(mx1 - mn1);
      mx0 = mn0; mx1 = mn1;
      Z0 *= c0; Z1 *= c1;
#pragma unroll
      for (int r = 0; r < 16; ++r) {
        o0[r] *= c0; o1[r] *= c0;
        o2[r] *= c1; o3[r] *= c1;
      }
    }
    float zl0 = 0.f, zl1 = 0.f;
#pragma unroll
    for (int u = 0; u < 4; ++u) {
      const float a0 = EXP2(S0[4 * u + 0] - mx0);
      const float a1 = EXP2(S0[4 * u + 1] - mx0);
      const float a2 = EXP2(S0[4 * u + 2] - mx0);
      const float a3 = EXP2(S0[4 * u + 3] - mx0);
      zl0 += (a0 + a1) + (a2 + a3);
      const half2v lo = pkrtz(a0, a1);
      const half2v hi2 = pkrtz(a2, a3);
      half4v w4; w4[0] = lo[0]; w4[1] = lo[1]; w4[2] = hi2[0]; w4[3] = hi2[1];
      *(half4v*)(Pw + m * 40 + 4 * hi + 8 * u) = w4;
      const float b0 = EXP2(S1[4 * u + 0] - mx1);
      const float b1 = EXP2(S1[4 * u + 1] - mx1);
      const float b2 = EXP2(S1[4 * u + 2] - mx1);
      const float b3 = EXP2(S1[4 * u + 3] - mx1);
      zl1 += (b0 + b1) + (b2 + b3);
      const half2v lo2 = pkrtz(b0, b1);
      const half2v hi3 = pkrtz(b2, b3);
      half4v w5; w5[0] = lo2[0]; w5[1] = lo2[1]; w5[2] = hi3[0]; w5[3] = hi3[1];
      *(half4v*)(Pw + (32 + m) * 40 + 4 * hi + 8 * u) = w5;
    }
    Z0 += zl0; Z1 += zl1;
    // single LDS wait leg: all 4 P-frag reads together
    const half8 bP0 = *(const half8*)(Pw + m * 40 + 8 * hi);
    const half8 bP1 = *(const half8*)(Pw + m * 40 + 16 + 8 * hi);
    const half8 bQ0 = *(const half8*)(Pw + (32 + m) * 40 + 8 * hi);
    const half8 bQ1 = *(const half8*)(Pw + (32 + m) * 40 + 16 + 8 * hi);
    o0 = __builtin_amdgcn_mfma_f32_32x32x16_f16(hc[cur][0], bP0, o0, 0, 0, 0);
    o1 = __builtin_amdgcn_mfma_f32_32x32x16_f16(hc[cur][2], bP0, o1, 0, 0, 0);
    o2 = __builtin_amdgcn_mfma_f32_32x32x16_f16(hc[cur][0], bQ0, o2, 0, 0, 0);
    o3 = __builtin_amdgcn_mfma_f32_32x32x16_f16(hc[cur][2], bQ0, o3, 0, 0, 0);
    o0 = __builtin_amdgcn_mfma_f32_32x32x16_f16(hc[cur][1], bP1, o0, 0, 0, 0);
    o1 = __builtin_amdgcn_mfma_f32_32x32x16_f16(hc[cur][3], bP1, o1, 0, 0, 0);
    o2 = __builtin_amdgcn_mfma_f32_32x32x16_f16(hc[cur][1], bQ1, o2, 0, 0, 0);
    o3 = __builtin_amdgcn_mfma_f32_32x32x16_f16(hc[cur][3], bQ1, o3, 0, 0, 0);
  }

  // ---- merge the 8 l-partitions ----
  Z0 += __shfl_xor(Z0, 32, 64);
  Z1 += __shfl_xor(Z1, 32, 64);
  if (hi == 0) {
    redM[s][m] = mx0; redM[s][m + 32] = mx1;
    redZ[s][m] = Z0;  redZ[s][m + 32] = Z1;
  }
  __syncthreads();
  float M0 = redM[0][m], M1 = redM[0][m + 32];
#pragma unroll
  for (int i = 1; i < 8; ++i) {
    M0 = fmaxf(M0, redM[i][m]);
    M1 = fmaxf(M1, redM[i][m + 32]);
  }
  const float sc0 = EXP2(mx0 - M0);
  const float sc1 = EXP2(mx1 - M1);
  if (s < 4) {
#pragma unroll
    for (int r = 0; r < 16; ++r) {
      const int o = 4 * hi + 8 * (r >> 2) + (r & 3);
      obuf4[s][o][m] = sc0 * o0[r];
      obuf4[s][o + 32][m] = sc0 * o1[r];
      obuf4[s][o][m + 32] = sc1 * o2[r];
      obuf4[s][o + 32][m + 32] = sc1 * o3[r];
    }
  }
  __syncthreads();
  if (s >= 4) {
#pragma unroll
    for (int r = 0; r < 16; ++r) {
      const int o = 4 * hi + 8 * (r >> 2) + (r & 3);
      obuf4[s - 4][o][m] += sc0 * o0[r];
      obuf4[s - 4][o + 32][m] += sc0 * o1[r];
      obuf4[s - 4][o][m + 32] += sc1 * o2[r];
      obuf4[s - 4][o + 32][m + 32] += sc1 * o3[r];
    }
  }
  __syncthreads();

  // epilogue: out = gamma * O / Zt + v1
  const float gam = gamma_p[0];
  const int me = t & 63;   // m column
  const int og = t >> 6;   // 0..7
  float M = redM[0][me];
#pragma unroll
  for (int i = 1; i < 8; ++i) M = fmaxf(M, redM[i][me]);
  float Zt = 0.f;
#pragma unroll
  for (int i = 0; i < 8; ++i) Zt += EXP2(redM[i][me] - M) * redZ[i][me];
  const float inv = 1.0f / Zt;
#pragma unroll
  for (int i = 0; i < 8; ++i) {
    const int o = og * 8 + i;
    const float val = obuf4[0][o][me] + obuf4[1][o][me] +
                      obuf4[2][o][me] + obuf4[3][o][me];
    const size_t g = ((size_t)b * CO_ + o) * L_ + m0 + me;
    out[g] = gam * val * inv + v1N[g];
  }
}

extern "C" void kernel_launch(void* const* d_in, const int* in_sizes, int n_in,
                              void* d_out, int out_size, void* d_ws,
                              size_t ws_size, hipStream_t stream) {
  const float* x = (const float*)d_in[0];
  const float* Wq = (const float*)d_in[1];
  const float* Wk = (const float*)d_in[2];
  const float* Wv = (const float*)d_in[3];
  const float* Wv1 = (const float*)d_in[4];
  const float* gamma = (const float*)d_in[5];
  float* out = (float*)d_out;

  _Float16* fPack = (_Float16*)d_ws;
  _Float16* gPack = fPack + (size_t)B_ * L_ * CO_;
  _Float16* hPack = gPack + (size_t)B_ * L_ * CO_;
  float* v1N = (float*)(hPack + (size_t)B_ * L_ * CO_);

  proj_mfma<<<dim3(L_ / 32, B_), 256, 0, stream>>>(x, Wq, Wk, Wv, Wv1, fPack,
                                                   gPack, hPack, v1N);
  attn_mfma<<<256, 512, 0, stream>>>(fPack, gPack, hPack, v1N, gamma, out);
}

// Round 8
// 105.765 us; speedup vs baseline: 1.0523x; 1.0523x over previous
//
#include <hip/hip_runtime.h>
#include <math.h>

// Problem constants (fixed by the reference):
#define B_ 4
#define C_ 192
#define L_ 4096
#define CO_ 64
#define LOG2E 1.44269504088896340736f

using half8 = __attribute__((ext_vector_type(8))) _Float16;
using half4v = __attribute__((ext_vector_type(4))) _Float16;
using half2v = __attribute__((ext_vector_type(2))) _Float16;
using f32x16 = __attribute__((ext_vector_type(16))) float;

#if __has_builtin(__builtin_amdgcn_exp2f)
#define EXP2(x) __builtin_amdgcn_exp2f(x)
#else
#define EXP2(x) exp2f(x)
#endif

__device__ inline half2v pkrtz(float a, float b) {
  return __builtin_bit_cast(half2v, __builtin_amdgcn_cvt_pkrtz(a, b));
}

// ---------------------------------------------------------------------------
// ws layout (halfs unless noted; fully rewritten every call):
//   Wpack : [w][og][ks][lane]x8  4*2*12*64*8 = 49152 (96 KB, frag order)
//   fPack : [b][T][ks][lane]x8   4*128*4*64*8 = 2 MB (A-frags of f, xLOG2E)
//   gPack : [b][T][ks][lane]x8                = 2 MB (B-frags of g)
//   hPack : [b][T][j][lane]x8                 = 2 MB (A-frags of h)
//   v1N   : [b][o][l] f32                     = 4 MB
// All hot-loop loads are lane-contiguous 1-KB fragment loads (8 lines/instr).
// ---------------------------------------------------------------------------

// Kernel 0: pack weights into MFMA fragment order, fp32 -> f16.
// Wpack[w][og][ks][lane][j] = W_w[og*32+(lane&31)][ks*16+(lane>>5)*8+j]
// (times LOG2E for w==0).  One-time cost; proj then reads lane-contiguous.
__global__ __launch_bounds__(256) void wpack_kernel(
    const float* __restrict__ Wq, const float* __restrict__ Wk,
    const float* __restrict__ Wv, const float* __restrict__ Wv1,
    _Float16* __restrict__ Wpack) {
  const int tid = blockIdx.x * 256 + threadIdx.x;  // 24*256 = 6144
  const int w = tid / 1536;
  const int rem = tid % 1536;
  const int og = rem / 768;
  const int ks = (rem % 768) / 64;
  const int lane = rem % 64;
  const float* src = (w == 0) ? Wq : (w == 1) ? Wk : (w == 2) ? Wv : Wv1;
  const float s = (w == 0) ? LOG2E : 1.0f;
  const int row = og * 32 + (lane & 31);
  const int col = ks * 16 + (lane >> 5) * 8;
  const float* p = src + row * C_ + col;
  const float4 a = *(const float4*)(p);
  const float4 c = *(const float4*)(p + 4);
  half8 o;
  half2v t;
  t = pkrtz(a.x * s, a.y * s); o[0] = t[0]; o[1] = t[1];
  t = pkrtz(a.z * s, a.w * s); o[2] = t[0]; o[3] = t[1];
  t = pkrtz(c.x * s, c.y * s); o[4] = t[0]; o[5] = t[1];
  t = pkrtz(c.z * s, c.w * s); o[6] = t[0]; o[7] = t[1];
  *(half8*)(Wpack + (size_t)tid * 8) = o;
}

// ---------------------------------------------------------------------------
// Kernel 1: projections via MFMA.  Grid (L/32=T, B), 256 thr (4 waves).
// x staged f32 [c][l] via global_load_lds; W frags from Wpack (8-line loads)
// issued BEFORE the barrier so they overlap the x DMA.
// Wave 0 (f): swapped operands D[l][o] -> LDS transpose -> fPack frags.
// Wave 1 (g): swapped operands D[l][o] -> LDS transpose -> gPack frags.
// Wave 2 (h): normal D[o][l] -> LDS transpose -> hPack frags.
// Wave 3 (v1): normal -> direct [o][l] f32 stores.
// ---------------------------------------------------------------------------
__global__ __launch_bounds__(256) void proj_mfma(
    const float* __restrict__ x, const _Float16* __restrict__ Wpack,
    _Float16* __restrict__ fPack, _Float16* __restrict__ gPack,
    _Float16* __restrict__ hPack, float* __restrict__ v1N) {
  __shared__ __align__(16) float xs[C_ * 32];       // [c][l] rows of 128 B
  __shared__ __align__(16) _Float16 fl[32 * 72];    // wave-0 transpose buffer
  __shared__ __align__(16) _Float16 gl[32 * 72];    // wave-1 transpose buffer
  __shared__ __align__(16) _Float16 hl[64 * 40];    // wave-2 transpose buffer
  const int b = blockIdx.y, T = blockIdx.x, l0 = T * 32;
  const int t = threadIdx.x;
  const int lane = t & 63, w = t >> 6;
  const int m = lane & 31, hi = lane >> 5;

  {  // stage x: wave w loads c-range [48w, 48w+48)
    const float* xb = x + (size_t)b * C_ * L_ + l0;
    const int c0 = w * 48;
#pragma unroll
    for (int i = 0; i < 6; ++i) {
      const int cc = c0 + i * 8;
      const float* gp = xb + (size_t)(cc + (lane >> 3)) * L_ + (lane & 7) * 4;
      __builtin_amdgcn_global_load_lds(
          (const __attribute__((address_space(1))) void*)gp,
          (__attribute__((address_space(3))) void*)&xs[cc * 32], 16, 0, 0);
    }
  }

  // W frags (fragment-packed, lane-contiguous; overlaps the DMA above)
  const _Float16* Wp = Wpack + (size_t)w * 1536 * 8;
  half8 wf[2][12];
#pragma unroll
  for (int og = 0; og < 2; ++og)
#pragma unroll
    for (int ks = 0; ks < 12; ++ks)
      wf[og][ks] =
          *(const half8*)(Wp + ((size_t)(og * 12 + ks) * 64 + lane) * 8);
  __syncthreads();

  if (w < 2) {
    // D[l][o] = x^T W^T : A = x^T rows l, B = W^T cols o.
    f32x16 acc0 = {}, acc1 = {};
#pragma unroll
    for (int ks = 0; ks < 12; ++ks) {
      const float* xr = &xs[(ks * 16 + hi * 8) * 32 + m];
      half8 aF;
#pragma unroll
      for (int e = 0; e < 8; e += 2) {
        const half2v hp = pkrtz(xr[e * 32], xr[(e + 1) * 32]);
        aF[e] = hp[0]; aF[e + 1] = hp[1];
      }
      acc0 = __builtin_amdgcn_mfma_f32_32x32x16_f16(aF, wf[0][ks], acc0, 0, 0, 0);
      acc1 = __builtin_amdgcn_mfma_f32_32x32x16_f16(aF, wf[1][ks], acc1, 0, 0, 0);
    }
    // transpose via per-wave LDS, then fragment-packed lane-contiguous stores
    _Float16* buf = (w == 0) ? fl : gl;
#pragma unroll
    for (int r = 0; r < 16; ++r) {
      const int l = 4 * hi + 8 * (r >> 2) + (r & 3);
      buf[l * 72 + m] = (_Float16)acc0[r];
      buf[l * 72 + 32 + m] = (_Float16)acc1[r];
    }
    _Float16* dst = ((w == 0) ? fPack : gPack) +
                    (size_t)b * L_ * CO_ + (size_t)T * 4 * 64 * 8;
#pragma unroll
    for (int ks = 0; ks < 4; ++ks) {
      const half8 v =
          *(const half8*)&buf[(lane & 31) * 72 + ks * 16 + (lane >> 5) * 8];
      *(half8*)(dst + ((size_t)ks * 64 + lane) * 8) = v;
    }
  } else {
    // D[o][l] = W x : A = W rows o, B = x cols l.
    const int lg = l0 + m;
    for (int oh = 0; oh < 2; ++oh) {
      f32x16 acc = {};
#pragma unroll
      for (int ks = 0; ks < 12; ++ks) {
        const float* xr = &xs[(16 * ks + 8 * hi) * 32 + m];
        half8 bF;
#pragma unroll
        for (int e = 0; e < 8; e += 2) {
          const half2v hp = pkrtz(xr[e * 32], xr[(e + 1) * 32]);
          bF[e] = hp[0]; bF[e + 1] = hp[1];
        }
        acc = __builtin_amdgcn_mfma_f32_32x32x16_f16(wf[oh][ks], bF, acc, 0, 0, 0);
      }
      if (w == 2) {
#pragma unroll
        for (int r = 0; r < 16; ++r) {
          const int o = 32 * oh + 4 * hi + 8 * (r >> 2) + (r & 3);
          hl[o * 40 + m] = (_Float16)acc[r];
        }
      } else {
#pragma unroll
        for (int r = 0; r < 16; ++r) {
          const int o = 32 * oh + 4 * hi + 8 * (r >> 2) + (r & 3);
          v1N[((size_t)b * CO_ + o) * L_ + lg] = acc[r];
        }
      }
    }
    if (w == 2) {  // fragment-packed stores
      _Float16* dst = hPack + (size_t)b * L_ * CO_ + (size_t)T * 4 * 64 * 8;
#pragma unroll
      for (int j = 0; j < 4; ++j) {  // j = oh*2 + ks
        const int oh2 = j >> 1, ks2 = j & 1;
        const half8 v = *(const half8*)&hl[(32 * oh2 + (lane & 31)) * 40 +
                                           ks2 * 16 + (lane >> 5) * 8];
        *(half8*)(dst + ((size_t)j * 64 + lane) * 8) = v;
      }
    }
  }
}

// ---------------------------------------------------------------------------
// Kernel 2: flash attention, fragment-packed loads, fused dual softmax.
// 256 blocks (1/CU; XCD pair -> batch), 512 thr = 8 waves.
// Wave s: l-partition [512s, 512s+512), 16 steps of 32 l x 64 m.
// Per step: 8 S-MFMA, ONE fused softmax body for both m-halves (both max
// trees, both exp blocks, all 8 P-writes -> single LDS wait leg -> 4
// P-reads -> 8 O-MFMA).  Register-double-buffered f/h frags.
// ---------------------------------------------------------------------------
__global__ __launch_bounds__(512, 2) void attn_mfma(
    const _Float16* __restrict__ fPack, const _Float16* __restrict__ gPack,
    const _Float16* __restrict__ hPack, const float* __restrict__ v1N,
    const float* __restrict__ gamma_p, float* __restrict__ out) {
  __shared__ __align__(16) _Float16 Pl[8][64 * 40];  // per-wave P, 2 m-halves
  __shared__ float obuf4[4][CO_][65];
  __shared__ float redM[8][64];
  __shared__ float redZ[8][64];

  const int id = blockIdx.x;                   // 256 blocks
  const int b = (id >> 1) & 3;                 // XCD pair -> batch
  const int mt = ((id & 1) << 5) | (id >> 3);  // 0..63
  const int m0 = mt * 64;
  const int t = threadIdx.x;
  const int lane = t & 63, s = t >> 6;
  const int m = lane & 31, hi = lane >> 5;

  const _Float16* fT = fPack + (size_t)b * L_ * CO_;
  const _Float16* hT = hPack + (size_t)b * L_ * CO_;
  _Float16* Pw = &Pl[s][0];

  // loop-invariant g B-frags for both m-halves (lane-contiguous frag loads)
  half8 gf0[4], gf1[4];
  {
    const _Float16* gp = gPack + (size_t)b * L_ * CO_ +
                         (size_t)(2 * mt) * 4 * 64 * 8 + lane * 8;
#pragma unroll
    for (int ks = 0; ks < 4; ++ks) {
      gf0[ks] = *(const half8*)(gp + (size_t)ks * 64 * 8);
      gf1[ks] = *(const half8*)(gp + (size_t)(4 + ks) * 64 * 8);
    }
  }

  f32x16 o0 = {}, o1 = {}, o2 = {}, o3 = {};
  float mx0 = -1e30f, Z0 = 0.f, mx1 = -1e30f, Z1 = 0.f;

  const int T0 = s * 16;
  half8 fc[2][4], hc[2][4];
  {  // initial frags, step 0
    const _Float16* fp = fT + ((size_t)T0 * 4 * 64 + lane) * 8;
    const _Float16* hp = hT + ((size_t)T0 * 4 * 64 + lane) * 8;
#pragma unroll
    for (int ks = 0; ks < 4; ++ks) {
      fc[0][ks] = *(const half8*)(fp + (size_t)ks * 64 * 8);
      hc[0][ks] = *(const half8*)(hp + (size_t)ks * 64 * 8);
    }
  }

#pragma unroll 2
  for (int stp = 0; stp < 16; ++stp) {
    const int cur = stp & 1, nxt = cur ^ 1;
    {  // prefetch step+1 (tail reads run into the next ws buffer: harmless)
      const int Tn = T0 + stp + 1;
      const _Float16* fp = fT + ((size_t)Tn * 4 * 64 + lane) * 8;
      const _Float16* hp = hT + ((size_t)Tn * 4 * 64 + lane) * 8;
#pragma unroll
      for (int ks = 0; ks < 4; ++ks) {
        fc[nxt][ks] = *(const half8*)(fp + (size_t)ks * 64 * 8);
        hc[nxt][ks] = *(const half8*)(hp + (size_t)ks * 64 * 8);
      }
    }
    // S for both m-halves (scores in log2 units via Wq pre-scale)
    f32x16 S0 = {}, S1 = {};
#pragma unroll
    for (int ks = 0; ks < 4; ++ks) {
      S0 = __builtin_amdgcn_mfma_f32_32x32x16_f16(fc[cur][ks], gf0[ks], S0, 0, 0, 0);
      S1 = __builtin_amdgcn_mfma_f32_32x32x16_f16(fc[cur][ks], gf1[ks], S1, 0, 0, 0);
    }
    // ---- fused dual online softmax ----
    float t0 = S0[0], t1 = S1[0];
#pragma unroll
    for (int r = 1; r < 16; ++r) {
      t0 = fmaxf(t0, S0[r]);
      t1 = fmaxf(t1, S1[r]);
    }
    t0 = fmaxf(t0, __shfl_xor(t0, 32, 64));
    t1 = fmaxf(t1, __shfl_xor(t1, 32, 64));
    if (__any(t0 > mx0 || t1 > mx1)) {
      const float mn0 = fmaxf(mx0, t0), mn1 = fmaxf(mx1, t1);
      const float c0 = EXP2(mx0 - mn0), c1 = EXP2(mx1 - mn1);
      mx0 = mn0; mx1 = mn1;
      Z0 *= c0; Z1 *= c1;
#pragma unroll
      for (int r = 0; r < 16; ++r) {
        o0[r] *= c0; o1[r] *= c0;
        o2[r] *= c1; o3[r] *= c1;
      }
    }
    float zl0 = 0.f, zl1 = 0.f;
#pragma unroll
    for (int u = 0; u < 4; ++u) {
      const float a0 = EXP2(S0[4 * u + 0] - mx0);
      const float a1 = EXP2(S0[4 * u + 1] - mx0);
      const float a2 = EXP2(S0[4 * u + 2] - mx0);
      const float a3 = EXP2(S0[4 * u + 3] - mx0);
      zl0 += (a0 + a1) + (a2 + a3);
      const half2v lo = pkrtz(a0, a1);
      const half2v hi2 = pkrtz(a2, a3);
      half4v w4; w4[0] = lo[0]; w4[1] = lo[1]; w4[2] = hi2[0]; w4[3] = hi2[1];
      *(half4v*)(Pw + m * 40 + 4 * hi + 8 * u) = w4;
      const float b0 = EXP2(S1[4 * u + 0] - mx1);
      const float b1 = EXP2(S1[4 * u + 1] - mx1);
      const float b2 = EXP2(S1[4 * u + 2] - mx1);
      const float b3 = EXP2(S1[4 * u + 3] - mx1);
      zl1 += (b0 + b1) + (b2 + b3);
      const half2v lo2 = pkrtz(b0, b1);
      const half2v hi3 = pkrtz(b2, b3);
      half4v w5; w5[0] = lo2[0]; w5[1] = lo2[1]; w5[2] = hi3[0]; w5[3] = hi3[1];
      *(half4v*)(Pw + (32 + m) * 40 + 4 * hi + 8 * u) = w5;
    }
    Z0 += zl0; Z1 += zl1;
    // single LDS wait leg: all 4 P-frag reads together
    const half8 bP0 = *(const half8*)(Pw + m * 40 + 8 * hi);
    const half8 bP1 = *(const half8*)(Pw + m * 40 + 16 + 8 * hi);
    const half8 bQ0 = *(const half8*)(Pw + (32 + m) * 40 + 8 * hi);
    const half8 bQ1 = *(const half8*)(Pw + (32 + m) * 40 + 16 + 8 * hi);
    o0 = __builtin_amdgcn_mfma_f32_32x32x16_f16(hc[cur][0], bP0, o0, 0, 0, 0);
    o1 = __builtin_amdgcn_mfma_f32_32x32x16_f16(hc[cur][2], bP0, o1, 0, 0, 0);
    o2 = __builtin_amdgcn_mfma_f32_32x32x16_f16(hc[cur][0], bQ0, o2, 0, 0, 0);
    o3 = __builtin_amdgcn_mfma_f32_32x32x16_f16(hc[cur][2], bQ0, o3, 0, 0, 0);
    o0 = __builtin_amdgcn_mfma_f32_32x32x16_f16(hc[cur][1], bP1, o0, 0, 0, 0);
    o1 = __builtin_amdgcn_mfma_f32_32x32x16_f16(hc[cur][3], bP1, o1, 0, 0, 0);
    o2 = __builtin_amdgcn_mfma_f32_32x32x16_f16(hc[cur][1], bQ1, o2, 0, 0, 0);
    o3 = __builtin_amdgcn_mfma_f32_32x32x16_f16(hc[cur][3], bQ1, o3, 0, 0, 0);
  }

  // ---- merge the 8 l-partitions ----
  Z0 += __shfl_xor(Z0, 32, 64);
  Z1 += __shfl_xor(Z1, 32, 64);
  if (hi == 0) {
    redM[s][m] = mx0; redM[s][m + 32] = mx1;
    redZ[s][m] = Z0;  redZ[s][m + 32] = Z1;
  }
  __syncthreads();
  float M0 = redM[0][m], M1 = redM[0][m + 32];
#pragma unroll
  for (int i = 1; i < 8; ++i) {
    M0 = fmaxf(M0, redM[i][m]);
    M1 = fmaxf(M1, redM[i][m + 32]);
  }
  const float sc0 = EXP2(mx0 - M0);
  const float sc1 = EXP2(mx1 - M1);
  if (s < 4) {
#pragma unroll
    for (int r = 0; r < 16; ++r) {
      const int o = 4 * hi + 8 * (r >> 2) + (r & 3);
      obuf4[s][o][m] = sc0 * o0[r];
      obuf4[s][o + 32][m] = sc0 * o1[r];
      obuf4[s][o][m + 32] = sc1 * o2[r];
      obuf4[s][o + 32][m + 32] = sc1 * o3[r];
    }
  }
  __syncthreads();
  if (s >= 4) {
#pragma unroll
    for (int r = 0; r < 16; ++r) {
      const int o = 4 * hi + 8 * (r >> 2) + (r & 3);
      obuf4[s - 4][o][m] += sc0 * o0[r];
      obuf4[s - 4][o + 32][m] += sc0 * o1[r];
      obuf4[s - 4][o][m + 32] += sc1 * o2[r];
      obuf4[s - 4][o + 32][m + 32] += sc1 * o3[r];
    }
  }
  __syncthreads();

  // epilogue: out = gamma * O / Zt + v1
  const float gam = gamma_p[0];
  const int me = t & 63;   // m column
  const int og = t >> 6;   // 0..7
  float M = redM[0][me];
#pragma unroll
  for (int i = 1; i < 8; ++i) M = fmaxf(M, redM[i][me]);
  float Zt = 0.f;
#pragma unroll
  for (int i = 0; i < 8; ++i) Zt += EXP2(redM[i][me] - M) * redZ[i][me];
  const float inv = 1.0f / Zt;
#pragma unroll
  for (int i = 0; i < 8; ++i) {
    const int o = og * 8 + i;
    const float val = obuf4[0][o][me] + obuf4[1][o][me] +
                      obuf4[2][o][me] + obuf4[3][o][me];
    const size_t g = ((size_t)b * CO_ + o) * L_ + m0 + me;
    out[g] = gam * val * inv + v1N[g];
  }
}

extern "C" void kernel_launch(void* const* d_in, const int* in_sizes, int n_in,
                              void* d_out, int out_size, void* d_ws,
                              size_t ws_size, hipStream_t stream) {
  const float* x = (const float*)d_in[0];
  const float* Wq = (const float*)d_in[1];
  const float* Wk = (const float*)d_in[2];
  const float* Wv = (const float*)d_in[3];
  const float* Wv1 = (const float*)d_in[4];
  const float* gamma = (const float*)d_in[5];
  float* out = (float*)d_out;

  _Float16* Wpack = (_Float16*)d_ws;                 // 49152 halfs (96 KB)
  _Float16* fPack = Wpack + (size_t)4 * 1536 * 8;
  _Float16* gPack = fPack + (size_t)B_ * L_ * CO_;
  _Float16* hPack = gPack + (size_t)B_ * L_ * CO_;
  float* v1N = (float*)(hPack + (size_t)B_ * L_ * CO_);

  wpack_kernel<<<24, 256, 0, stream>>>(Wq, Wk, Wv, Wv1, Wpack);
  proj_mfma<<<dim3(L_ / 32, B_), 256, 0, stream>>>(x, Wpack, fPack, gPack,
                                                   hPack, v1N);
  attn_mfma<<<256, 512, 0, stream>>>(fPack, gPack, hPack, v1N, gamma, out);
}

// Round 10
// 105.089 us; speedup vs baseline: 1.0591x; 1.0064x over previous
//
#include <hip/hip_runtime.h>
#include <math.h>

// Problem constants (fixed by the reference):
#define B_ 4
#define C_ 192
#define L_ 4096
#define CO_ 64
#define LOG2E 1.44269504088896340736f

using half8 = __attribute__((ext_vector_type(8))) _Float16;
using half4v = __attribute__((ext_vector_type(4))) _Float16;
using half2v = __attribute__((ext_vector_type(2))) _Float16;
using f32x16 = __attribute__((ext_vector_type(16))) float;

#if __has_builtin(__builtin_amdgcn_exp2f)
#define EXP2(x) __builtin_amdgcn_exp2f(x)
#else
#define EXP2(x) exp2f(x)
#endif

__device__ inline half2v pkrtz(float a, float b) {
  return __builtin_bit_cast(half2v, __builtin_amdgcn_cvt_pkrtz(a, b));
}

// ---------------------------------------------------------------------------
// ws layout (halfs unless noted; fully rewritten every call):
//   Wpack : [w][og][ks][lane]x8  4*2*12*64*8 = 49152 (96 KB, frag order)
//   fPack : [b][T][ks][lane]x8   = 2 MB (A-frags of f, xLOG2E)
//   gPack : [b][T][ks][lane]x8   = 2 MB (B-frags of g)
//   hPack : [b][T][j][lane]x8    = 2 MB (A-frags of h)
//   v1N   : [b][o][l] f32        = 4 MB
// ---------------------------------------------------------------------------

// Kernel 0: pack weights into MFMA fragment order, fp32 -> f16.
__global__ __launch_bounds__(256) void wpack_kernel(
    const float* __restrict__ Wq, const float* __restrict__ Wk,
    const float* __restrict__ Wv, const float* __restrict__ Wv1,
    _Float16* __restrict__ Wpack) {
  const int tid = blockIdx.x * 256 + threadIdx.x;  // 24*256 = 6144
  const int w = tid / 1536;
  const int rem = tid % 1536;
  const int og = rem / 768;
  const int ks = (rem % 768) / 64;
  const int lane = rem % 64;
  const float* src = (w == 0) ? Wq : (w == 1) ? Wk : (w == 2) ? Wv : Wv1;
  const float s = (w == 0) ? LOG2E : 1.0f;
  const int row = og * 32 + (lane & 31);
  const int col = ks * 16 + (lane >> 5) * 8;
  const float* p = src + row * C_ + col;
  const float4 a = *(const float4*)(p);
  const float4 c = *(const float4*)(p + 4);
  half8 o;
  half2v t;
  t = pkrtz(a.x * s, a.y * s); o[0] = t[0]; o[1] = t[1];
  t = pkrtz(a.z * s, a.w * s); o[2] = t[0]; o[3] = t[1];
  t = pkrtz(c.x * s, c.y * s); o[4] = t[0]; o[5] = t[1];
  t = pkrtz(c.z * s, c.w * s); o[6] = t[0]; o[7] = t[1];
  *(half8*)(Wpack + (size_t)tid * 8) = o;
}

// ---------------------------------------------------------------------------
// Kernel 1: projections via MFMA.  Grid (L/32=T, B), 256 thr (4 waves).
// x staged as f16 TRANSPOSED tile xT[l][c] (VGPR+cvt staging); ALL waves use
// swapped operands D[l][o] = x^T W^T with b128 A-frag reads.
// Outputs routed through small LDS transposes.
// ---------------------------------------------------------------------------
__global__ __launch_bounds__(256) void proj_mfma(
    const float* __restrict__ x, const _Float16* __restrict__ Wpack,
    _Float16* __restrict__ fPack, _Float16* __restrict__ gPack,
    _Float16* __restrict__ hPack, float* __restrict__ v1N) {
  __shared__ __align__(16) _Float16 xT[32][200];   // [l][c], stride 200 halfs
  __shared__ __align__(16) _Float16 fl[32 * 72];
  __shared__ __align__(16) _Float16 gl[32 * 72];
  __shared__ __align__(16) _Float16 hl[64 * 40];
  __shared__ float vl[64][33];
  const int b = blockIdx.y, T = blockIdx.x, l0 = T * 32;
  const int t = threadIdx.x;
  const int lane = t & 63, w = t >> 6;
  const int m = lane & 31, hi = lane >> 5;
  const int lr = lane & 31, rp = lane >> 5;

  // W frags (lane-contiguous; independent of LDS)
  const _Float16* Wp = Wpack + (size_t)w * 1536 * 8;
  half8 wf[2][12];
#pragma unroll
  for (int og = 0; og < 2; ++og)
#pragma unroll
    for (int ks = 0; ks < 12; ++ks)
      wf[og][ks] =
          *(const half8*)(Wp + ((size_t)(og * 12 + ks) * 64 + lane) * 8);

  {  // stage x: wave w converts c-rows [48w, 48w+48) into xT[l][c] f16
    const float* xb = x + (size_t)b * C_ * L_ + l0 + lr;
    const int c0 = w * 48;
#pragma unroll
    for (int i = 0; i < 24; ++i) {
      const int c = c0 + 2 * i + rp;
      xT[lr][c] = (_Float16)xb[(size_t)c * L_];
    }
  }
  __syncthreads();

  // A-frags: x^T rows l (b128 reads), shared by all waves
  half8 aF[12];
#pragma unroll
  for (int ks = 0; ks < 12; ++ks)
    aF[ks] = *(const half8*)&xT[m][ks * 16 + hi * 8];

  f32x16 acc0 = {}, acc1 = {};
#pragma unroll
  for (int ks = 0; ks < 12; ++ks) {
    acc0 = __builtin_amdgcn_mfma_f32_32x32x16_f16(aF[ks], wf[0][ks], acc0, 0, 0, 0);
    acc1 = __builtin_amdgcn_mfma_f32_32x32x16_f16(aF[ks], wf[1][ks], acc1, 0, 0, 0);
  }
  // C-layout: lane m holds o-columns m (acc0) and m+32 (acc1),
  // rows l = 4*hi + 8*(r>>2) + (r&3).

  if (w < 2) {
    // f/g: transpose to [l][o] rows, then fragment-packed stores
    _Float16* buf = (w == 0) ? fl : gl;
#pragma unroll
    for (int r = 0; r < 16; ++r) {
      const int l = 4 * hi + 8 * (r >> 2) + (r & 3);
      buf[l * 72 + m] = (_Float16)acc0[r];
      buf[l * 72 + 32 + m] = (_Float16)acc1[r];
    }
    _Float16* dst = ((w == 0) ? fPack : gPack) +
                    (size_t)b * L_ * CO_ + (size_t)T * 4 * 64 * 8;
#pragma unroll
    for (int ks = 0; ks < 4; ++ks) {
      const half8 v =
          *(const half8*)&buf[(lane & 31) * 72 + ks * 16 + (lane >> 5) * 8];
      *(half8*)(dst + ((size_t)ks * 64 + lane) * 8) = v;
    }
  } else if (w == 2) {
    // h: transpose to hl[o][l], then fragment-packed stores
#pragma unroll
    for (int r = 0; r < 16; ++r) {
      const int l = 4 * hi + 8 * (r >> 2) + (r & 3);
      hl[m * 40 + l] = (_Float16)acc0[r];
      hl[(32 + m) * 40 + l] = (_Float16)acc1[r];
    }
    _Float16* dst = hPack + (size_t)b * L_ * CO_ + (size_t)T * 4 * 64 * 8;
#pragma unroll
    for (int j = 0; j < 4; ++j) {  // j = oh*2 + ks
      const int oh2 = j >> 1, ks2 = j & 1;
      const half8 v = *(const half8*)&hl[(32 * oh2 + (lane & 31)) * 40 +
                                         ks2 * 16 + (lane >> 5) * 8];
      *(half8*)(dst + ((size_t)j * 64 + lane) * 8) = v;
    }
  } else {
    // v1: transpose to vl[o][l] f32 (stride 33), dense stores.
    // 32 iterations: o = 2*i + rp covers ALL o in [0,64).  (R9 bug: 16.)
#pragma unroll
    for (int r = 0; r < 16; ++r) {
      const int l = 4 * hi + 8 * (r >> 2) + (r & 3);
      vl[m][l] = acc0[r];
      vl[32 + m][l] = acc1[r];
    }
#pragma unroll
    for (int i = 0; i < 32; ++i) {
      const int o = 2 * i + rp;
      v1N[((size_t)b * CO_ + o) * L_ + l0 + lr] = vl[o][lr];
    }
  }
}

// ---------------------------------------------------------------------------
// Kernel 2: flash attention, S-AHEAD SOFTWARE PIPELINE.
// 256 blocks (1/CU; XCD pair -> batch), 512 thr = 8 waves.
// Iteration t: compute S(t+1) (from frags prefetched at t-1) FIRST, then
// softmax(t) -> P -> O(t).  The softmax consumer always has a full step of
// slack behind its producer; MFMA and VALU streams decouple.
// ---------------------------------------------------------------------------
__global__ __launch_bounds__(512, 2) void attn_mfma(
    const _Float16* __restrict__ fPack, const _Float16* __restrict__ gPack,
    const _Float16* __restrict__ hPack, const float* __restrict__ v1N,
    const float* __restrict__ gamma_p, float* __restrict__ out) {
  __shared__ __align__(16) _Float16 Pl[8][64 * 40];
  __shared__ float obuf4[4][CO_][65];
  __shared__ float redM[8][64];
  __shared__ float redZ[8][64];

  const int id = blockIdx.x;                   // 256 blocks
  const int b = (id >> 1) & 3;                 // XCD pair -> batch
  const int mt = ((id & 1) << 5) | (id >> 3);  // 0..63
  const int m0 = mt * 64;
  const int t = threadIdx.x;
  const int lane = t & 63, s = t >> 6;
  const int m = lane & 31, hi = lane >> 5;

  const _Float16* fT = fPack + (size_t)b * L_ * CO_;
  const _Float16* hT = hPack + (size_t)b * L_ * CO_;
  _Float16* Pw = &Pl[s][0];

  // loop-invariant g B-frags for both m-halves
  half8 gf0[4], gf1[4];
  {
    const _Float16* gp = gPack + (size_t)b * L_ * CO_ +
                         (size_t)(2 * mt) * 4 * 64 * 8 + lane * 8;
#pragma unroll
    for (int ks = 0; ks < 4; ++ks) {
      gf0[ks] = *(const half8*)(gp + (size_t)ks * 64 * 8);
      gf1[ks] = *(const half8*)(gp + (size_t)(4 + ks) * 64 * 8);
    }
  }

  f32x16 o0 = {}, o1 = {}, o2 = {}, o3 = {};
  float mx0 = -1e30f, Z0 = 0.f, mx1 = -1e30f, Z1 = 0.f;

  const int T0 = s * 16;
  half8 fc[2][4];
  f32x16 Sv0[2], Sv1[2];

  {  // prologue: fc[0] <- chunk 0; S(chunk 0); fc[1] <- chunk 1
    const _Float16* fp = fT + ((size_t)T0 * 4 * 64 + lane) * 8;
#pragma unroll
    for (int ks = 0; ks < 4; ++ks)
      fc[0][ks] = *(const half8*)(fp + (size_t)ks * 64 * 8);
    f32x16 z = {};
    Sv0[0] = z; Sv1[0] = z;
#pragma unroll
    for (int ks = 0; ks < 4; ++ks) {
      Sv0[0] = __builtin_amdgcn_mfma_f32_32x32x16_f16(fc[0][ks], gf0[ks], Sv0[0], 0, 0, 0);
      Sv1[0] = __builtin_amdgcn_mfma_f32_32x32x16_f16(fc[0][ks], gf1[ks], Sv1[0], 0, 0, 0);
    }
    const _Float16* fp1 = fT + ((size_t)(T0 + 1) * 4 * 64 + lane) * 8;
#pragma unroll
    for (int ks = 0; ks < 4; ++ks)
      fc[1][ks] = *(const half8*)(fp1 + (size_t)ks * 64 * 8);
  }

#pragma unroll 2
  for (int stp = 0; stp < 16; ++stp) {
    const int cur = stp & 1, nxt = cur ^ 1;
    // h frags for chunk stp (used at the end of this iteration)
    half8 hc[4];
    {
      const _Float16* hp = hT + ((size_t)(T0 + stp) * 4 * 64 + lane) * 8;
#pragma unroll
      for (int ks = 0; ks < 4; ++ks)
        hc[ks] = *(const half8*)(hp + (size_t)ks * 64 * 8);
    }
    // S for chunk stp+1 from fc[nxt] (loaded one iteration ago)
    {
      f32x16 z = {};
      Sv0[nxt] = z; Sv1[nxt] = z;
#pragma unroll
      for (int ks = 0; ks < 4; ++ks) {
        Sv0[nxt] = __builtin_amdgcn_mfma_f32_32x32x16_f16(fc[nxt][ks], gf0[ks], Sv0[nxt], 0, 0, 0);
        Sv1[nxt] = __builtin_amdgcn_mfma_f32_32x32x16_f16(fc[nxt][ks], gf1[ks], Sv1[nxt], 0, 0, 0);
      }
    }
    // prefetch fc[cur] <- chunk stp+2 (tail overruns into adjacent ws: unused)
    {
      const _Float16* fp = fT + ((size_t)(T0 + stp + 2) * 4 * 64 + lane) * 8;
#pragma unroll
      for (int ks = 0; ks < 4; ++ks)
        fc[cur][ks] = *(const half8*)(fp + (size_t)ks * 64 * 8);
    }
    // ---- fused dual softmax on S(chunk stp) ----
    const f32x16 S0 = Sv0[cur], S1 = Sv1[cur];
    float t0 = S0[0], t1 = S1[0];
#pragma unroll
    for (int r = 1; r < 16; ++r) {
      t0 = fmaxf(t0, S0[r]);
      t1 = fmaxf(t1, S1[r]);
    }
    t0 = fmaxf(t0, __shfl_xor(t0, 32, 64));
    t1 = fmaxf(t1, __shfl_xor(t1, 32, 64));
    if (__any(t0 > mx0 || t1 > mx1)) {
      const float mn0 = fmaxf(mx0, t0), mn1 = fmaxf(mx1, t1);
      const float c0 = EXP2(mx0 - mn0), c1 = EXP2(mx1 - mn1);
      mx0 = mn0; mx1 = mn1;
      Z0 *= c0; Z1 *= c1;
#pragma unroll
      for (int r = 0; r < 16; ++r) {
        o0[r] *= c0; o1[r] *= c0;
        o2[r] *= c1; o3[r] *= c1;
      }
    }
    float zl0 = 0.f, zl1 = 0.f;
#pragma unroll
    for (int u = 0; u < 4; ++u) {
      const float a0 = EXP2(S0[4 * u + 0] - mx0);
      const float a1 = EXP2(S0[4 * u + 1] - mx0);
      const float a2 = EXP2(S0[4 * u + 2] - mx0);
      const float a3 = EXP2(S0[4 * u + 3] - mx0);
      zl0 += (a0 + a1) + (a2 + a3);
      const half2v lo = pkrtz(a0, a1);
      const half2v hi2 = pkrtz(a2, a3);
      half4v w4; w4[0] = lo[0]; w4[1] = lo[1]; w4[2] = hi2[0]; w4[3] = hi2[1];
      *(half4v*)(Pw + m * 40 + 4 * hi + 8 * u) = w4;
      const float b0 = EXP2(S1[4 * u + 0] - mx1);
      const float b1 = EXP2(S1[4 * u + 1] - mx1);
      const float b2 = EXP2(S1[4 * u + 2] - mx1);
      const float b3 = EXP2(S1[4 * u + 3] - mx1);
      zl1 += (b0 + b1) + (b2 + b3);
      const half2v lo2 = pkrtz(b0, b1);
      const half2v hi3 = pkrtz(b2, b3);
      half4v w5; w5[0] = lo2[0]; w5[1] = lo2[1]; w5[2] = hi3[0]; w5[3] = hi3[1];
      *(half4v*)(Pw + (32 + m) * 40 + 4 * hi + 8 * u) = w5;
    }
    Z0 += zl0; Z1 += zl1;
    // P frag reads + O MFMAs
    const half8 bP0 = *(const half8*)(Pw + m * 40 + 8 * hi);
    const half8 bP1 = *(const half8*)(Pw + m * 40 + 16 + 8 * hi);
    const half8 bQ0 = *(const half8*)(Pw + (32 + m) * 40 + 8 * hi);
    const half8 bQ1 = *(const half8*)(Pw + (32 + m) * 40 + 16 + 8 * hi);
    o0 = __builtin_amdgcn_mfma_f32_32x32x16_f16(hc[0], bP0, o0, 0, 0, 0);
    o1 = __builtin_amdgcn_mfma_f32_32x32x16_f16(hc[2], bP0, o1, 0, 0, 0);
    o2 = __builtin_amdgcn_mfma_f32_32x32x16_f16(hc[0], bQ0, o2, 0, 0, 0);
    o3 = __builtin_amdgcn_mfma_f32_32x32x16_f16(hc[2], bQ0, o3, 0, 0, 0);
    o0 = __builtin_amdgcn_mfma_f32_32x32x16_f16(hc[1], bP1, o0, 0, 0, 0);
    o1 = __builtin_amdgcn_mfma_f32_32x32x16_f16(hc[3], bP1, o1, 0, 0, 0);
    o2 = __builtin_amdgcn_mfma_f32_32x32x16_f16(hc[1], bQ1, o2, 0, 0, 0);
    o3 = __builtin_amdgcn_mfma_f32_32x32x16_f16(hc[3], bQ1, o3, 0, 0, 0);
  }

  // ---- merge the 8 l-partitions ----
  Z0 += __shfl_xor(Z0, 32, 64);
  Z1 += __shfl_xor(Z1, 32, 64);
  if (hi == 0) {
    redM[s][m] = mx0; redM[s][m + 32] = mx1;
    redZ[s][m] = Z0;  redZ[s][m + 32] = Z1;
  }
  __syncthreads();
  float M0 = redM[0][m], M1 = redM[0][m + 32];
#pragma unroll
  for (int i = 1; i < 8; ++i) {
    M0 = fmaxf(M0, redM[i][m]);
    M1 = fmaxf(M1, redM[i][m + 32]);
  }
  const float sc0 = EXP2(mx0 - M0);
  const float sc1 = EXP2(mx1 - M1);
  if (s < 4) {
#pragma unroll
    for (int r = 0; r < 16; ++r) {
      const int o = 4 * hi + 8 * (r >> 2) + (r & 3);
      obuf4[s][o][m] = sc0 * o0[r];
      obuf4[s][o + 32][m] = sc0 * o1[r];
      obuf4[s][o][m + 32] = sc1 * o2[r];
      obuf4[s][o + 32][m + 32] = sc1 * o3[r];
    }
  }
  __syncthreads();
  if (s >= 4) {
#pragma unroll
    for (int r = 0; r < 16; ++r) {
      const int o = 4 * hi + 8 * (r >> 2) + (r & 3);
      obuf4[s - 4][o][m] += sc0 * o0[r];
      obuf4[s - 4][o + 32][m] += sc0 * o1[r];
      obuf4[s - 4][o][m + 32] += sc1 * o2[r];
      obuf4[s - 4][o + 32][m + 32] += sc1 * o3[r];
    }
  }
  __syncthreads();

  // epilogue: out = gamma * O / Zt + v1
  const float gam = gamma_p[0];
  const int me = t & 63;   // m column
  const int og = t >> 6;   // 0..7
  float M = redM[0][me];
#pragma unroll
  for (int i = 1; i < 8; ++i) M = fmaxf(M, redM[i][me]);
  float Zt = 0.f;
#pragma unroll
  for (int i = 0; i < 8; ++i) Zt += EXP2(redM[i][me] - M) * redZ[i][me];
  const float inv = 1.0f / Zt;
#pragma unroll
  for (int i = 0; i < 8; ++i) {
    const int o = og * 8 + i;
    const float val = obuf4[0][o][me] + obuf4[1][o][me] +
                      obuf4[2][o][me] + obuf4[3][o][me];
    const size_t g = ((size_t)b * CO_ + o) * L_ + m0 + me;
    out[g] = gam * val * inv + v1N[g];
  }
}

extern "C" void kernel_launch(void* const* d_in, const int* in_sizes, int n_in,
                              void* d_out, int out_size, void* d_ws,
                              size_t ws_size, hipStream_t stream) {
  const float* x = (const float*)d_in[0];
  const float* Wq = (const float*)d_in[1];
  const float* Wk = (const float*)d_in[2];
  const float* Wv = (const float*)d_in[3];
  const float* Wv1 = (const float*)d_in[4];
  const float* gamma = (const float*)d_in[5];
  float* out = (float*)d_out;

  _Float16* Wpack = (_Float16*)d_ws;                 // 49152 halfs (96 KB)
  _Float16* fPack = Wpack + (size_t)4 * 1536 * 8;
  _Float16* gPack = fPack + (size_t)B_ * L_ * CO_;
  _Float16* hPack = gPack + (size_t)B_ * L_ * CO_;
  float* v1N = (float*)(hPack + (size_t)B_ * L_ * CO_);

  wpack_kernel<<<24, 256, 0, stream>>>(Wq, Wk, Wv, Wv1, Wpack);
  proj_mfma<<<dim3(L_ / 32, B_), 256, 0, stream>>>(x, Wpack, fPack, gPack,
                                                   hPack, v1N);
  attn_mfma<<<256, 512, 0, stream>>>(fPack, gPack, hPack, v1N, gamma, out);
}